// Round 1
// 538.582 us; speedup vs baseline: 1.2625x; 1.2625x over previous
//
#include <hip/hip_runtime.h>
#include <hip/hip_bf16.h>
#include <stdint.h>

// Problem constants (match reference)
#define B_SZ   16384
#define IN_DIM 1024
#define H1     2048
#define H2     2048
#define HID    1024
#define SPEC_H 2048
#define NE     8
#define MAX_TILES 136   // 8 XCDs x 17 tiles exactly

typedef __bf16 bf16x8 __attribute__((ext_vector_type(8)));
typedef float  f32x4  __attribute__((ext_vector_type(4)));
typedef ushort us8    __attribute__((ext_vector_type(8)));

__device__ __forceinline__ ushort f2bf(float f) {
  uint32_t u = __float_as_uint(f);
  u += 0x7FFF + ((u >> 16) & 1);
  return (ushort)(u >> 16);
}

__device__ __forceinline__ void gl_lds16(const void* g, void* l) {
  __builtin_amdgcn_global_load_lds(
      (const __attribute__((address_space(1))) void*)g,
      (__attribute__((address_space(3))) void*)l, 16, 0, 0);
}

// ---------------- fused prep: 4 transposes + x-cast + count/out-init --------

struct TransDesc { const float* src; ushort* dst; int K, N, nx, base; };

struct PrepArgs {
  TransDesc td[4];
  const float* x; ushort* xb;
  const int* d; int* counts; const float* sb2; float* out;
  int castBase;   // first cast block
  int cntBase;    // first count block
};

__global__ void prep_all(PrepArgs pa) {
  int g = blockIdx.x;
  int t = threadIdx.x;
  if (g >= pa.cntBase) {
    // count + out-init: 64 blocks x 256.
    // LDS histogram first: 16384 same-line global atomics -> 512 total.
    __shared__ int hist[NE];
    if (t < NE) hist[t] = 0;
    __syncthreads();
    int i = (g - pa.cntBase) * 256 + t;
    int e = pa.d[i];
    atomicAdd(&hist[e], 1);
    pa.out[i] = pa.sb2[e];     // spec_b2[e][0]
    __syncthreads();
    if (t < NE) atomicAdd(&pa.counts[t], hist[t]);
    return;
  }
  if (g >= pa.castBase) {
    // x fp32 -> bf16, 16 elems/thread (4x float4 in flight)
    size_t i = (size_t)(g - pa.castBase) * 4096 + (size_t)t * 16;
    float4 v0 = *(const float4*)(pa.x + i);
    float4 v1 = *(const float4*)(pa.x + i + 4);
    float4 v2 = *(const float4*)(pa.x + i + 8);
    float4 v3 = *(const float4*)(pa.x + i + 12);
    uint32_t p0 = f2bf(v0.x) | ((uint32_t)f2bf(v0.y) << 16);
    uint32_t p1 = f2bf(v0.z) | ((uint32_t)f2bf(v0.w) << 16);
    uint32_t p2 = f2bf(v1.x) | ((uint32_t)f2bf(v1.y) << 16);
    uint32_t p3 = f2bf(v1.z) | ((uint32_t)f2bf(v1.w) << 16);
    uint32_t p4 = f2bf(v2.x) | ((uint32_t)f2bf(v2.y) << 16);
    uint32_t p5 = f2bf(v2.z) | ((uint32_t)f2bf(v2.w) << 16);
    uint32_t p6 = f2bf(v3.x) | ((uint32_t)f2bf(v3.y) << 16);
    uint32_t p7 = f2bf(v3.z) | ((uint32_t)f2bf(v3.w) << 16);
    int4 pkA = {(int)p0, (int)p1, (int)p2, (int)p3};
    int4 pkB = {(int)p4, (int)p5, (int)p6, (int)p7};
    *(int4*)(pa.xb + i) = pkA;
    *(int4*)(pa.xb + i + 8) = pkB;
    return;
  }
  // weight transpose-cast (64x64 tile)
  __shared__ float tile[64][65];  // tile[n][k]
  int wsel = 0;
#pragma unroll
  for (int i = 1; i < 4; ++i)
    if (g >= pa.td[i].base) wsel = i;
  TransDesc dd = pa.td[wsel];
  int local = g - dd.base;
  int per = dd.nx * (dd.K >> 6);
  int z = local / per;
  int r = local - z * per;
  int bx = r % dd.nx, by = r / dd.nx;
  int n0 = bx * 64, k0 = by * 64;
  const float* src = dd.src + (size_t)z * dd.K * dd.N;
  ushort* dst = dd.dst + (size_t)z * dd.K * dd.N;
  int lk = t >> 4;
  int ln4 = (t & 15) * 4;
#pragma unroll
  for (int j = 0; j < 4; ++j) {
    int k = lk + j * 16;
    float4 v = *(const float4*)(src + (size_t)(k0 + k) * dd.N + n0 + ln4);
    tile[ln4 + 0][k] = v.x;
    tile[ln4 + 1][k] = v.y;
    tile[ln4 + 2][k] = v.z;
    tile[ln4 + 3][k] = v.w;
  }
  __syncthreads();
  // write phase: 16B stores, 8 k-values/lane, 2 passes
  int kc = (t & 7) * 8;
  int nb = t >> 3;
#pragma unroll
  for (int j = 0; j < 2; ++j) {
    int nn = nb + j * 32;
    us8 o;
#pragma unroll
    for (int q = 0; q < 8; ++q) o[q] = f2bf(tile[nn][kc + q]);
    *(us8*)(dst + (size_t)(n0 + nn) * dd.K + k0 + kc) = o;
  }
}

// ---------------- routing ----------------

__global__ void build_k(const int* __restrict__ counts, int* __restrict__ catalog,
                        int* __restrict__ poff, int* __restrict__ cursors) {
  if (threadIdx.x == 0) {
    int off = 0;
    for (int e = 0; e < NE; ++e) {
      poff[e] = off * 128;
      int nt = (counts[e] + 127) >> 7;
      for (int i = 0; i < nt; ++i) catalog[off + i] = e;
      off += nt;
      cursors[e] = 0;
    }
    for (int i = off; i < MAX_TILES; ++i) catalog[i] = -1;
  }
}

// block-level scatter: wave ballot rank + per-wave LDS counts + 8 atomics/block
__global__ void scatter_k(const int* __restrict__ d, const int* __restrict__ poff,
                          int* __restrict__ cursors, int* __restrict__ perm) {
  __shared__ int wcnt[4][NE];
  __shared__ int basee[NE];
  int t = threadIdx.x;
  int i = blockIdx.x * 256 + t;
  int e = d[i];
  int w = t >> 6, lane = t & 63;
  uint64_t mymask = 0;
#pragma unroll
  for (int ee = 0; ee < NE; ++ee) {
    uint64_t mm = __ballot(e == ee);
    if (lane == 0) wcnt[w][ee] = __popcll(mm);
    if (e == ee) mymask = mm;
  }
  int rank = __popcll(mymask & ((1ull << lane) - 1ull));
  __syncthreads();
  if (t < NE) {
    int s = 0;
#pragma unroll
    for (int ww = 0; ww < 4; ++ww) { int c = wcnt[ww][t]; wcnt[ww][t] = s; s += c; }
    basee[t] = atomicAdd(&cursors[t], s);
  }
  __syncthreads();
  int pos = basee[e] + wcnt[w][e] + rank;
  perm[poff[e] + pos] = i;
}

// ---------------- 128x128 bf16 GEMM (G1/G3) ----------------

template <int RELU>
__global__ __launch_bounds__(256, 2) void gemm_bias(
    const ushort* __restrict__ A, const ushort* __restrict__ Bt,
    const float* __restrict__ bias, ushort* __restrict__ C,
    int M, int N, int K, int lognx) {
  __shared__ __align__(16) ushort lA[128 * 64];
  __shared__ __align__(16) ushort lB[128 * 64];
  const int t = threadIdx.x;
  const int h = blockIdx.x;
  const int g = h >> 3;
  const int nx = 1 << lognx;
  const int by = (h & 7) + ((g >> lognx) << 3);
  const int bx = g & (nx - 1);
  const int m0 = by * 128, n0 = bx * 128;
  const int w = t >> 6, lane = t & 63;
  const int wm = (w >> 1) * 64, wn = (w & 1) * 64;
  const int q = lane >> 4, rl = lane & 15;

  f32x4 acc[4][4];
#pragma unroll
  for (int mi = 0; mi < 4; ++mi)
#pragma unroll
    for (int ni = 0; ni < 4; ++ni) acc[mi][ni] = 0.0f;

  const int row_s = t >> 3;
  const int pch_s = t & 7;

  for (int k0 = 0; k0 < K; k0 += 64) {
    __syncthreads();
#pragma unroll
    for (int j = 0; j < 4; ++j) {
      int row = j * 32 + row_s;
      int gch = pch_s ^ (row & 7);
      gl_lds16(A + (size_t)(m0 + row) * K + k0 + gch * 8, lA + j * 2048 + w * 512);
      gl_lds16(Bt + (size_t)(n0 + row) * K + k0 + gch * 8, lB + j * 2048 + w * 512);
    }
    __syncthreads();
#pragma unroll
    for (int kk = 0; kk < 2; ++kk) {
      bf16x8 af[4], bfr[4];
#pragma unroll
      for (int i = 0; i < 4; ++i) {
        int pc = (kk * 4 + q) ^ (rl & 7);
        af[i]  = __builtin_bit_cast(bf16x8, *(const int4*)(lA + (wm + i * 16 + rl) * 64 + pc * 8));
        bfr[i] = __builtin_bit_cast(bf16x8, *(const int4*)(lB + (wn + i * 16 + rl) * 64 + pc * 8));
      }
#pragma unroll
      for (int mi = 0; mi < 4; ++mi)
#pragma unroll
        for (int ni = 0; ni < 4; ++ni)
          acc[mi][ni] = __builtin_amdgcn_mfma_f32_16x16x32_bf16(af[mi], bfr[ni], acc[mi][ni], 0, 0, 0);
    }
  }

  float bv[4];
#pragma unroll
  for (int ni = 0; ni < 4; ++ni) bv[ni] = bias[n0 + wn + ni * 16 + rl];
#pragma unroll
  for (int mi = 0; mi < 4; ++mi) {
    int rg = m0 + wm + mi * 16 + q * 4;
#pragma unroll
    for (int r = 0; r < 4; ++r) {
#pragma unroll
      for (int ni = 0; ni < 4; ++ni) {
        float v = acc[mi][ni][r] + bv[ni];
        if (RELU) v = fmaxf(v, 0.0f);
        C[(size_t)(rg + r) * N + n0 + wn + ni * 16 + rl] = f2bf(v);
      }
    }
  }
}

// ---------------- 256x128 bf16 GEMM (G2) ----------------

template <int RELU>
__global__ __launch_bounds__(256, 2) void gemm_bias_256(
    const ushort* __restrict__ A, const ushort* __restrict__ Bt,
    const float* __restrict__ bias, ushort* __restrict__ C,
    int M, int N, int K, int lognx) {
  __shared__ __align__(16) ushort lA[256 * 64];
  __shared__ __align__(16) ushort lB[128 * 64];
  const int t = threadIdx.x;
  const int h = blockIdx.x;
  const int g = h >> 3;
  const int nx = 1 << lognx;
  const int by = (h & 7) + ((g >> lognx) << 3);
  const int bx = g & (nx - 1);
  const int m0 = by * 256, n0 = bx * 128;
  const int w = t >> 6, lane = t & 63;
  const int wm = (w >> 1) * 128, wn = (w & 1) * 64;
  const int q = lane >> 4, rl = lane & 15;

  f32x4 acc[8][4];
#pragma unroll
  for (int mi = 0; mi < 8; ++mi)
#pragma unroll
    for (int ni = 0; ni < 4; ++ni) acc[mi][ni] = 0.0f;

  const int row_s = t >> 3;
  const int pch_s = t & 7;

  for (int k0 = 0; k0 < K; k0 += 64) {
    __syncthreads();
#pragma unroll
    for (int j = 0; j < 8; ++j) {
      int row = j * 32 + row_s;
      int gch = pch_s ^ (row & 7);
      gl_lds16(A + (size_t)(m0 + row) * K + k0 + gch * 8, lA + j * 2048 + w * 512);
    }
#pragma unroll
    for (int j = 0; j < 4; ++j) {
      int row = j * 32 + row_s;
      int gch = pch_s ^ (row & 7);
      gl_lds16(Bt + (size_t)(n0 + row) * K + k0 + gch * 8, lB + j * 2048 + w * 512);
    }
    __syncthreads();
#pragma unroll
    for (int kk = 0; kk < 2; ++kk) {
      bf16x8 bfr[4];
#pragma unroll
      for (int i = 0; i < 4; ++i) {
        int pc = (kk * 4 + q) ^ (rl & 7);
        bfr[i] = __builtin_bit_cast(bf16x8, *(const int4*)(lB + (wn + i * 16 + rl) * 64 + pc * 8));
      }
#pragma unroll
      for (int mi = 0; mi < 8; ++mi) {
        int pc = (kk * 4 + q) ^ (rl & 7);
        bf16x8 af = __builtin_bit_cast(bf16x8, *(const int4*)(lA + (wm + mi * 16 + rl) * 64 + pc * 8));
#pragma unroll
        for (int ni = 0; ni < 4; ++ni)
          acc[mi][ni] = __builtin_amdgcn_mfma_f32_16x16x32_bf16(af, bfr[ni], acc[mi][ni], 0, 0, 0);
      }
    }
  }

  float bv[4];
#pragma unroll
  for (int ni = 0; ni < 4; ++ni) bv[ni] = bias[n0 + wn + ni * 16 + rl];
#pragma unroll
  for (int mi = 0; mi < 8; ++mi) {
    int rg = m0 + wm + mi * 16 + q * 4;
#pragma unroll
    for (int r = 0; r < 4; ++r) {
#pragma unroll
      for (int ni = 0; ni < 4; ++ni) {
        float v = acc[mi][ni][r] + bv[ni];
        if (RELU) v = fmaxf(v, 0.0f);
        C[(size_t)(rg + r) * N + n0 + wn + ni * 16 + rl] = f2bf(v);
      }
    }
  }
}

// ---------------- fused expert stage (bounds-aware, XCD-partitioned) --------

__global__ __launch_bounds__(256, 2) void expert_fused(
    const ushort* __restrict__ Z, const ushort* __restrict__ W1t,
    const float* __restrict__ b1, const float* __restrict__ w2,
    const int* __restrict__ perm, const int* __restrict__ catalog,
    const int* __restrict__ poff, const int* __restrict__ counts,
    float* __restrict__ out) {
  const int id = blockIdx.x;
  const int tile = (id & 7) * 17 + ((id >> 3) >> 4);
  const int ycol = (id >> 3) & 15;
  int e = catalog[tile];
  if (e < 0) return;
  __shared__ __align__(16) ushort lA[128 * 64];
  __shared__ __align__(16) ushort lB[128 * 64];
  __shared__ int perml[128];
  __shared__ float ysum[128];
  const int t = threadIdx.x;
  if (t < 128) {
    int slot = tile * 128 + t;
    int rel = slot - poff[e];
    perml[t] = (rel < counts[e]) ? perm[slot] : -1;
    ysum[t] = 0.0f;
  }
  __syncthreads();

  const int n0 = ycol * 128;
  const ushort* Bt = W1t + (size_t)e * SPEC_H * HID;
  const float* b1e = b1 + (size_t)e * SPEC_H;
  const float* w2e = w2 + (size_t)e * SPEC_H;
  const int w = t >> 6, lane = t & 63;
  const int wm = (w >> 1) * 64, wn = (w & 1) * 64;
  const int q = lane >> 4, rl = lane & 15;

  f32x4 acc[4][4];
#pragma unroll
  for (int mi = 0; mi < 4; ++mi)
#pragma unroll
    for (int ni = 0; ni < 4; ++ni) acc[mi][ni] = 0.0f;

  const int row_s = t >> 3;
  const int pch_s = t & 7;

  for (int k0 = 0; k0 < HID; k0 += 64) {
    __syncthreads();
#pragma unroll
    for (int j = 0; j < 4; ++j) {
      int row = j * 32 + row_s;
      int gch = pch_s ^ (row & 7);
      int zr = perml[row];
      zr = zr < 0 ? 0 : zr;
      gl_lds16(Z + (size_t)zr * HID + k0 + gch * 8, lA + j * 2048 + w * 512);
      gl_lds16(Bt + (size_t)(n0 + row) * HID + k0 + gch * 8, lB + j * 2048 + w * 512);
    }
    __syncthreads();
#pragma unroll
    for (int kk = 0; kk < 2; ++kk) {
      bf16x8 af[4], bfr[4];
#pragma unroll
      for (int i = 0; i < 4; ++i) {
        int pc = (kk * 4 + q) ^ (rl & 7);
        af[i]  = __builtin_bit_cast(bf16x8, *(const int4*)(lA + (wm + i * 16 + rl) * 64 + pc * 8));
        bfr[i] = __builtin_bit_cast(bf16x8, *(const int4*)(lB + (wn + i * 16 + rl) * 64 + pc * 8));
      }
#pragma unroll
      for (int mi = 0; mi < 4; ++mi)
#pragma unroll
        for (int ni = 0; ni < 4; ++ni)
          acc[mi][ni] = __builtin_amdgcn_mfma_f32_16x16x32_bf16(af[mi], bfr[ni], acc[mi][ni], 0, 0, 0);
    }
  }

  float w2v[4], b1v[4];
#pragma unroll
  for (int ni = 0; ni < 4; ++ni) {
    int n = n0 + wn + ni * 16 + rl;
    w2v[ni] = w2e[n];
    b1v[ni] = b1e[n];
  }
#pragma unroll
  for (int mi = 0; mi < 4; ++mi) {
#pragma unroll
    for (int r = 0; r < 4; ++r) {
      float p = 0.0f;
#pragma unroll
      for (int ni = 0; ni < 4; ++ni) {
        float h = acc[mi][ni][r] + b1v[ni];
        h = fmaxf(h, 0.0f);
        p += h * w2v[ni];
      }
      p += __shfl_xor(p, 1);
      p += __shfl_xor(p, 2);
      p += __shfl_xor(p, 4);
      p += __shfl_xor(p, 8);
      if (rl == 0) atomicAdd(&ysum[wm + mi * 16 + q * 4 + r], p);
    }
  }
  __syncthreads();
  if (t < 128) {
    int orow = perml[t];
    if (orow >= 0) atomicAdd(&out[orow], ysum[t]);
  }
}

// ---------------- host ----------------

extern "C" void kernel_launch(void* const* d_in, const int* in_sizes, int n_in,
                              void* d_out, int out_size, void* d_ws, size_t ws_size,
                              hipStream_t stream) {
  const float* x   = (const float*)d_in[0];
  const int*   d   = (const int*)d_in[1];
  const float* eW0 = (const float*)d_in[2];
  const float* eb0 = (const float*)d_in[3];
  const float* eW1 = (const float*)d_in[4];
  const float* eb1 = (const float*)d_in[5];
  const float* eW2 = (const float*)d_in[6];
  const float* eb2 = (const float*)d_in[7];
  const float* sW1 = (const float*)d_in[8];
  const float* sb1 = (const float*)d_in[9];
  const float* sW2 = (const float*)d_in[10];
  const float* sb2 = (const float*)d_in[11];
  float* out = (float*)d_out;

  const size_t fixed = ((size_t)(4 + 8 + 4 + 32 + 32 + 32) << 20) + (1 << 20);
  int CH = 8192;
  if (ws_size >= fixed + (size_t)16384 * 8192) CH = 16384;   // ~241 MiB

  char* p = (char*)d_ws;
  ushort* W0t  = (ushort*)p; p += (size_t)IN_DIM * H1 * 2;
  ushort* W1t  = (ushort*)p; p += (size_t)H1 * H2 * 2;
  ushort* W2t  = (ushort*)p; p += (size_t)H2 * HID * 2;
  ushort* sW1t = (ushort*)p; p += (size_t)NE * HID * SPEC_H * 2;
  ushort* Zb   = (ushort*)p; p += (size_t)B_SZ * HID * 2;
  ushort* xb   = (ushort*)p; p += (size_t)B_SZ * IN_DIM * 2;
  int* counts  = (int*)p; p += 64;
  int* cursors = (int*)p; p += 64;
  int* poff    = (int*)p; p += 64;
  int* catalog = (int*)p; p += 1024;
  int* perm    = (int*)p; p += (size_t)MAX_TILES * 128 * 4;
  p = (char*)(((uintptr_t)p + 255) & ~(uintptr_t)255);
  ushort* z1 = (ushort*)p; p += (size_t)CH * H1 * 2;
  ushort* z2 = (ushort*)p; p += (size_t)CH * H2 * 2;

  hipMemsetAsync(counts, 0, 64, stream);

  // fused prep: transposes (6144) + x-cast (4096 @ 16/thread) + count (64)
  PrepArgs pa;
  pa.td[0] = {eW0, W0t, IN_DIM, H1, H1 / 64, 0};
  pa.td[1] = {eW1, W1t, H1, H2, H2 / 64, 512};
  pa.td[2] = {eW2, W2t, H2, HID, HID / 64, 1536};
  pa.td[3] = {sW1, sW1t, HID, SPEC_H, SPEC_H / 64, 2048};
  pa.x = x; pa.xb = xb;
  pa.d = d; pa.counts = counts; pa.sb2 = sb2; pa.out = out;
  pa.castBase = 6144;
  pa.cntBase = 6144 + 4096;
  prep_all<<<6144 + 4096 + 64, 256, 0, stream>>>(pa);

  build_k<<<1, 64, 0, stream>>>(counts, catalog, poff, cursors);
  scatter_k<<<B_SZ / 256, 256, 0, stream>>>(d, poff, cursors, perm);

  // encoder GEMMs (G2 merged back to a single launch)
  for (int c = 0; c < B_SZ; c += CH) {
    gemm_bias<1><<<(CH / 128) * (H1 / 128), 256, 0, stream>>>(
        xb + (size_t)c * IN_DIM, W0t, eb0, z1, CH, H1, IN_DIM, 4);
    gemm_bias_256<1><<<(CH / 256) * (H2 / 128), 256, 0, stream>>>(
        z1, W1t, eb1, z2, CH, H2, H1, 4);
    gemm_bias<0><<<(CH / 128) * (HID / 128), 256, 0, stream>>>(
        z2, W2t, eb2, Zb + (size_t)c * HID, CH, HID, H2, 3);
  }

  // fused expert stage
  expert_fused<<<MAX_TILES * 16, 256, 0, stream>>>(
      Zb, sW1t, sb1, sW2, perm, catalog, poff, counts, out);
}